// Round 1
// baseline (235.256 us; speedup 1.0000x reference)
//
#include <hip/hip_runtime.h>

// diff_lpc2rc: per-row backward Levinson recursion on N=16 fp32 values.
// Rows: 64 * 32768 = 2,097,152. Memory-bound: 268 MB total traffic -> ~43 us floor.

constexpr int N = 16;

__global__ __launch_bounds__(256) void lpc2rc_kernel(const float* __restrict__ x,
                                                     float* __restrict__ out,
                                                     int nrows) {
    const int r = blockIdx.x * blockDim.x + threadIdx.x;
    if (r >= nrows) return;

    const float4* __restrict__ in4 = (const float4*)x;
    float4* __restrict__ out4 = (float4*)out;

    // Load the 16-float row as 4x float4 (64 B per thread; wave covers 4 KB).
    float4 v0 = in4[r * 4 + 0];
    float4 v1 = in4[r * 4 + 1];
    float4 v2 = in4[r * 4 + 2];
    float4 v3 = in4[r * 4 + 3];

    float a[N];
    a[0]  = v0.x; a[1]  = v0.y; a[2]  = v0.z; a[3]  = v0.w;
    a[4]  = v1.x; a[5]  = v1.y; a[6]  = v1.z; a[7]  = v1.w;
    a[8]  = v2.x; a[9]  = v2.y; a[10] = v2.z; a[11] = v2.w;
    a[12] = v3.x; a[13] = v3.y; a[14] = v3.z; a[15] = v3.w;

    // Backward Levinson recursion, fully unrolled -> all indices constant,
    // everything lives in registers.
#pragma unroll
    for (int i = 1; i < N; ++i) {
        const int len = N - i;        // number of prefix elements updated
        const float k = a[len];
        const float inv = 1.0f / (1.0f - k * k);   // accurate fdiv (no fast-math)
        float t[N - 1];
#pragma unroll
        for (int m = 0; m < len; ++m) {
            t[m] = (a[m] - k * a[len - 1 - m]) * inv;
        }
#pragma unroll
        for (int m = 0; m < len; ++m) {
            a[m] = t[m];
        }
    }

    v0.x = a[0];  v0.y = a[1];  v0.z = a[2];  v0.w = a[3];
    v1.x = a[4];  v1.y = a[5];  v1.z = a[6];  v1.w = a[7];
    v2.x = a[8];  v2.y = a[9];  v2.z = a[10]; v2.w = a[11];
    v3.x = a[12]; v3.y = a[13]; v3.z = a[14]; v3.w = a[15];

    out4[r * 4 + 0] = v0;
    out4[r * 4 + 1] = v1;
    out4[r * 4 + 2] = v2;
    out4[r * 4 + 3] = v3;
}

extern "C" void kernel_launch(void* const* d_in, const int* in_sizes, int n_in,
                              void* d_out, int out_size, void* d_ws, size_t ws_size,
                              hipStream_t stream) {
    const float* x = (const float*)d_in[0];
    float* out = (float*)d_out;
    const int nrows = in_sizes[0] / N;   // 2,097,152

    const int block = 256;
    const int grid = (nrows + block - 1) / block;
    lpc2rc_kernel<<<grid, block, 0, stream>>>(x, out, nrows);
}

// Round 2
// 233.759 us; speedup vs baseline: 1.0064x; 1.0064x over previous
//
#include <hip/hip_runtime.h>

// diff_lpc2rc: per-row backward Levinson recursion on N=16 fp32 values.
// Rows: 64 * 32768 = 2,097,152. ~197 MB observed HBM traffic -> ~31 us floor.
//
// R2: shorten the dependent chain. (a) v_rcp_f32 instead of exact fp32 divide
// (threshold 0.296, rcp is ~1ulp -> plenty); (b) symmetric pairwise in-place
// update kills the t[] double-buffer copy.

constexpr int N = 16;

__global__ __launch_bounds__(256) void lpc2rc_kernel(const float* __restrict__ x,
                                                     float* __restrict__ out,
                                                     int nrows) {
    const int r = blockIdx.x * blockDim.x + threadIdx.x;
    if (r >= nrows) return;

    const float4* __restrict__ in4 = (const float4*)x;
    float4* __restrict__ out4 = (float4*)out;

    float4 v0 = in4[r * 4 + 0];
    float4 v1 = in4[r * 4 + 1];
    float4 v2 = in4[r * 4 + 2];
    float4 v3 = in4[r * 4 + 3];

    float a[N];
    a[0]  = v0.x; a[1]  = v0.y; a[2]  = v0.z; a[3]  = v0.w;
    a[4]  = v1.x; a[5]  = v1.y; a[6]  = v1.z; a[7]  = v1.w;
    a[8]  = v2.x; a[9]  = v2.y; a[10] = v2.z; a[11] = v2.w;
    a[12] = v3.x; a[13] = v3.y; a[14] = v3.z; a[15] = v3.w;

#pragma unroll
    for (int i = 1; i < N; ++i) {
        const int len = N - i;            // prefix length being updated
        const float k = a[len];
        const float inv = __builtin_amdgcn_rcpf(1.0f - k * k);  // ~1 ulp rcp
        // Pairwise symmetric update: (m, j=len-1-m) read old pair, write both.
#pragma unroll
        for (int m = 0; m < len / 2; ++m) {
            const int j = len - 1 - m;
            const float am = a[m];
            const float aj = a[j];
            a[m] = (am - k * aj) * inv;
            a[j] = (aj - k * am) * inv;
        }
        if (len & 1) {
            const int mid = len / 2;
            const float amid = a[mid];
            a[mid] = (amid - k * amid) * inv;
        }
    }

    v0.x = a[0];  v0.y = a[1];  v0.z = a[2];  v0.w = a[3];
    v1.x = a[4];  v1.y = a[5];  v1.z = a[6];  v1.w = a[7];
    v2.x = a[8];  v2.y = a[9];  v2.z = a[10]; v2.w = a[11];
    v3.x = a[12]; v3.y = a[13]; v3.z = a[14]; v3.w = a[15];

    out4[r * 4 + 0] = v0;
    out4[r * 4 + 1] = v1;
    out4[r * 4 + 2] = v2;
    out4[r * 4 + 3] = v3;
}

extern "C" void kernel_launch(void* const* d_in, const int* in_sizes, int n_in,
                              void* d_out, int out_size, void* d_ws, size_t ws_size,
                              hipStream_t stream) {
    const float* x = (const float*)d_in[0];
    float* out = (float*)d_out;
    const int nrows = in_sizes[0] / N;   // 2,097,152

    const int block = 256;
    const int grid = (nrows + block - 1) / block;
    lpc2rc_kernel<<<grid, block, 0, stream>>>(x, out, nrows);
}

// Round 3
// 229.698 us; speedup vs baseline: 1.0242x; 1.0177x over previous
//
#include <hip/hip_runtime.h>

// diff_lpc2rc: per-row backward Levinson recursion on N=16 fp32 values.
// Rows: 64 * 32768 = 2,097,152. ~197 MB observed HBM traffic -> ~31 us floor.
//
// R3: kill the 4x cacheline-transaction amplification. Previously each lane
// loaded/stored its own 64B row -> every dwordx4 instr touched 64 distinct
// cachelines (vs 16 coalesced). Now each wave stages its 4KB tile through a
// private LDS region: 4 coalesced global loads -> LDS scatter -> per-lane row
// gather (stride-17-dword rows: worst aliasing is lane l vs l+32 = 2-way =
// free) -> recursion in registers -> LDS -> coalesced stores.
// No __syncthreads: each wave touches only its own LDS region.

constexpr int N = 16;
constexpr int RS = 17;             // LDS row stride in dwords (68 B) - bank decorrelation
constexpr int WAVES_PER_WG = 4;    // 256 threads

__global__ __launch_bounds__(256) void lpc2rc_kernel(const float* __restrict__ x,
                                                     float* __restrict__ out,
                                                     int nrows) {
    __shared__ float lds[WAVES_PER_WG * 64 * RS];   // 17408 B

    const int tid  = threadIdx.x;
    const int wave = tid >> 6;
    const int lane = tid & 63;
    float* __restrict__ wlds = lds + wave * 64 * RS;

    const long long wave_row0 = ((long long)blockIdx.x * WAVES_PER_WG + wave) * 64;

    float a[N];

    if (wave_row0 + 64 <= (long long)nrows) {
        // ---- fast path: full 64-row tile, fully coalesced ----
        const float4* __restrict__ in4 = (const float4*)x;
        float4* __restrict__ out4 = (float4*)out;
        const long long base4 = wave_row0 * 4;   // float4 index of tile start

        // 4 coalesced loads: float4 #(base4 + c*64 + lane)
        float4 ld[4];
#pragma unroll
        for (int c = 0; c < 4; ++c)
            ld[c] = in4[base4 + (long long)(c * 64 + lane)];

        // scatter to LDS: float4 f = c*64+lane -> row 16c + (lane>>2), elems 4*(lane&3)..+3
#pragma unroll
        for (int c = 0; c < 4; ++c) {
            float* p = wlds + (16 * c + (lane >> 2)) * RS + 4 * (lane & 3);
            p[0] = ld[c].x; p[1] = ld[c].y; p[2] = ld[c].z; p[3] = ld[c].w;
        }

        // gather own row (lane l reads addr l*17+e: 2-way bank alias only)
        {
            const float* p = wlds + lane * RS;
#pragma unroll
            for (int e = 0; e < N; ++e) a[e] = p[e];
        }

        // ---- backward Levinson recursion, in registers ----
#pragma unroll
        for (int i = 1; i < N; ++i) {
            const int len = N - i;
            const float k = a[len];
            const float inv = __builtin_amdgcn_rcpf(1.0f - k * k);
#pragma unroll
            for (int m = 0; m < len / 2; ++m) {
                const int j = len - 1 - m;
                const float am = a[m];
                const float aj = a[j];
                a[m] = (am - k * aj) * inv;
                a[j] = (aj - k * am) * inv;
            }
            if (len & 1) {
                const int mid = len / 2;
                const float amid = a[mid];
                a[mid] = (amid - k * amid) * inv;
            }
        }

        // write row back to LDS
        {
            float* p = wlds + lane * RS;
#pragma unroll
            for (int e = 0; e < N; ++e) p[e] = a[e];
        }

        // coalesced stores (reverse of the load distribution)
#pragma unroll
        for (int c = 0; c < 4; ++c) {
            const float* p = wlds + (16 * c + (lane >> 2)) * RS + 4 * (lane & 3);
            float4 v;
            v.x = p[0]; v.y = p[1]; v.z = p[2]; v.w = p[3];
            out4[base4 + (long long)(c * 64 + lane)] = v;
        }
    } else {
        // ---- tail path: per-lane guarded (rare/absent for this shape) ----
        const long long r = wave_row0 + lane;
        if (r >= (long long)nrows) return;
        const float4* __restrict__ in4 = (const float4*)x;
        float4* __restrict__ out4 = (float4*)out;
        float4 v0 = in4[r * 4 + 0], v1 = in4[r * 4 + 1],
               v2 = in4[r * 4 + 2], v3 = in4[r * 4 + 3];
        a[0]=v0.x; a[1]=v0.y; a[2]=v0.z; a[3]=v0.w;
        a[4]=v1.x; a[5]=v1.y; a[6]=v1.z; a[7]=v1.w;
        a[8]=v2.x; a[9]=v2.y; a[10]=v2.z; a[11]=v2.w;
        a[12]=v3.x; a[13]=v3.y; a[14]=v3.z; a[15]=v3.w;
#pragma unroll
        for (int i = 1; i < N; ++i) {
            const int len = N - i;
            const float k = a[len];
            const float inv = __builtin_amdgcn_rcpf(1.0f - k * k);
#pragma unroll
            for (int m = 0; m < len / 2; ++m) {
                const int j = len - 1 - m;
                const float am = a[m], aj = a[j];
                a[m] = (am - k * aj) * inv;
                a[j] = (aj - k * am) * inv;
            }
            if (len & 1) {
                const int mid = len / 2;
                const float amid = a[mid];
                a[mid] = (amid - k * amid) * inv;
            }
        }
        v0.x=a[0]; v0.y=a[1]; v0.z=a[2]; v0.w=a[3];
        v1.x=a[4]; v1.y=a[5]; v1.z=a[6]; v1.w=a[7];
        v2.x=a[8]; v2.y=a[9]; v2.z=a[10]; v2.w=a[11];
        v3.x=a[12]; v3.y=a[13]; v3.z=a[14]; v3.w=a[15];
        out4[r * 4 + 0] = v0; out4[r * 4 + 1] = v1;
        out4[r * 4 + 2] = v2; out4[r * 4 + 3] = v3;
    }
}

extern "C" void kernel_launch(void* const* d_in, const int* in_sizes, int n_in,
                              void* d_out, int out_size, void* d_ws, size_t ws_size,
                              hipStream_t stream) {
    const float* x = (const float*)d_in[0];
    float* out = (float*)d_out;
    const int nrows = in_sizes[0] / N;                 // 2,097,152
    const int rows_per_wg = 64 * WAVES_PER_WG;         // 256
    const int grid = (nrows + rows_per_wg - 1) / rows_per_wg;   // 8192
    lpc2rc_kernel<<<grid, 256, 0, stream>>>(x, out, nrows);
}